// Round 1
// baseline (333.590 us; speedup 1.0000x reference)
//
#include <hip/hip_runtime.h>
#include <math.h>

#define HW (128*128)

typedef short short8 __attribute__((ext_vector_type(8)));
typedef float floatx4 __attribute__((ext_vector_type(4)));
typedef unsigned int uintx4 __attribute__((ext_vector_type(4)));

#define MFMA(a,b,c) __builtin_amdgcn_mfma_f32_16x16x32_bf16((a),(b),(c),0,0,0)

// workspace: [wt2: bf16 main weight 64x864][wmt: fp32 offset weight 594*27]
#define WT2_ELEMS  (64*864)          // [o][kk*96 + c], zero for c>=66
#define WT2_BYTES  (WT2_ELEMS*2)
#define WMT_ELEMS  (594*27)          // [(c*9+j)*27 + oc]
#define WS_NEED    (WT2_BYTES + WMT_ELEMS*4)

static __device__ __forceinline__ unsigned short f2bf(float x) {
    unsigned u = __float_as_uint(x);
    unsigned r = u + 0x7FFFu + ((u >> 16) & 1u);
    return (unsigned short)(r >> 16);
}

// pack 2 fp32 -> 2 bf16 (RNE) in one instruction; low16 = lo, high16 = hi
static __device__ __forceinline__ unsigned cvt_pk_bf16(float lo, float hi) {
    unsigned r;
    asm("v_cvt_pk_bf16_f32 %0, %1, %2" : "=v"(r) : "v"(lo), "v"(hi));
    return r;
}

__global__ __launch_bounds__(256) void prep_w(
    const float* __restrict__ weight, const float* __restrict__ w_om,
    unsigned short* __restrict__ wt2, float* __restrict__ wmt)
{
    int t = blockIdx.x * 256 + threadIdx.x;
    if (t < WT2_ELEMS) {
        int o = t / 864, k = t % 864;
        int kk = k / 96, c = k % 96;
        float v = (c < 66) ? weight[o * 594 + c * 9 + kk] : 0.0f;
        wt2[t] = f2bf(v);
    } else if (t < WT2_ELEMS + WMT_ELEMS) {
        int t2 = t - WT2_ELEMS;
        int oc = t2 % 27, ck = t2 / 27;
        wmt[t2] = w_om[oc * 594 + ck];
    }
}

// Phase A: fp32 VALU offset conv (verified path, unchanged).
// Phase B: cols as bf16 in LDS, XOR-swizzled 256B rows, double-buffered,
//          one barrier per tap; build(kk+1) overlaps MFMA(kk).
__global__ __launch_bounds__(256, 4) void dcn_hybrid3(
    const float* __restrict__ input,
    const unsigned short* __restrict__ wt2,
    const float* __restrict__ bias,
    const float* __restrict__ wmt,
    const float* __restrict__ b_om,
    float* __restrict__ out)
{
    // 2 buffers x 64 rows x 128 ushort (16 chunks of 8 bf16, swizzled) = 32 KB.
    // Aliases Phase-A s_red (6912 floats = 27648 B < 32768 B).
    __shared__ __align__(16) unsigned short s_col[2 * 64 * 128];
    __shared__ float s_offh[9 * 64], s_offw[9 * 64], s_maskf[9 * 64];
    float* s_red = (float*)s_col;

    const int tid  = threadIdx.x;
    const int lane = tid & 63;
    const int w    = tid >> 6;
    const int wu   = __builtin_amdgcn_readfirstlane(w);
    const int m15  = lane & 15;
    const int quad = lane >> 4;

    const int wo0 = blockIdx.x * 64;
    const int ho  = blockIdx.y;
    const int b   = blockIdx.z;
    const int wo  = wo0 + lane;
    const int p   = ho * 128 + wo;
    const float invH = 1.0f / 128.0f;

    const float* inb = input + (size_t)b * 64 * HW;

    // ---- 9 fixed-tap addresses / validity for pixel (ho, wo)
    int   a9[9];
    float okf[9], vy[9], vx[9];
#pragma unroll
    for (int j = 0; j < 9; ++j) {
        int y = ho - 1 + j / 3;
        int x = wo - 1 + j % 3;
        bool ok = ((unsigned)y < 128u) && ((unsigned)x < 128u);
        int yc = min(max(y, 0), 127), xc = min(max(x, 0), 127);
        a9[j]  = yc * 128 + xc;
        okf[j] = ok ? 1.0f : 0.0f;
        vy[j]  = ok ? y * invH : 0.0f;
        vx[j]  = ok ? (x * invH - 0.5f) : 0.0f;
    }

    const int nc = (wu < 2) ? 17 : 16;     // channels per wave: c = wu + 4*i

    // ---------------- Phase A: fp32 partial offset conv ----------------
    float om_part[27];
#pragma unroll
    for (int oc = 0; oc < 27; ++oc) om_part[oc] = 0.0f;

    for (int i = 0; i < nc; ++i) {
        int c = wu + 4 * i;
        float v[9];
        if (c < 64) {
            const float* pc = inb + c * HW;
#pragma unroll
            for (int j = 0; j < 9; ++j) v[j] = pc[a9[j]] * okf[j];
        } else if (c == 64) {
#pragma unroll
            for (int j = 0; j < 9; ++j) v[j] = vy[j];
        } else {
#pragma unroll
            for (int j = 0; j < 9; ++j) v[j] = vx[j];
        }
#pragma unroll
        for (int j = 0; j < 9; ++j) {
            const float* wp = wmt + (c * 9 + j) * 27;
#pragma unroll
            for (int oc = 0; oc < 27; ++oc)
                om_part[oc] = fmaf(v[j], wp[oc], om_part[oc]);
        }
    }
#pragma unroll
    for (int oc = 0; oc < 27; ++oc)
        s_red[(w * 27 + oc) * 64 + lane] = om_part[oc];
    __syncthreads();

    // ---- 4-way reduce + idx/mask epilogue + fp32 offsets/mask into LDS
    {
        float* out_idx = out + (size_t)8 * 64 * HW;
        float* out_msk = out_idx + (size_t)8 * 18 * HW;
        const float hg = ho * invH;
        const float wg = wo * invH - 0.5f;
        int oc0 = wu * 7;
        int noc = (wu == 3) ? 6 : 7;
        for (int t = 0; t < noc; ++t) {
            int oc = oc0 + t;
            float s = b_om[oc]
                    + s_red[(0 * 27 + oc) * 64 + lane]
                    + s_red[(1 * 27 + oc) * 64 + lane]
                    + s_red[(2 * 27 + oc) * 64 + lane]
                    + s_red[(3 * 27 + oc) * 64 + lane];
            if (oc < 9) {
                out_idx[((size_t)b * 18 + oc) * HW + p] = hg + (float)(oc / 3 - 1) + s;
                if (oc & 1) s_offw[(oc >> 1) * 64 + lane] = s;
                else        s_offh[(oc >> 1) * 64 + lane] = s;
            } else if (oc < 18) {
                out_idx[((size_t)b * 18 + oc) * HW + p] = wg + (float)((oc - 9) % 3 - 1) + s;
                if (oc & 1) s_offw[(oc >> 1) * 64 + lane] = s;
                else        s_offh[(oc >> 1) * 64 + lane] = s;
            } else {
                float mkv = 1.0f / (1.0f + __expf(-s));
                out_msk[((size_t)b * 9 + (oc - 18)) * HW + p] = mkv;
                s_maskf[(oc - 18) * 64 + lane] = mkv;
            }
        }
    }
    __syncthreads();   // s_red reads done; offsets/mask ready; s_col usable

    // ---------------- Phase B: bf16 swizzled cols + MFMA ----------------
    // Layout: buffer[buf] row r (pixel), logical chunk c (8 bf16 = 8 channels):
    //   ushort index = buf*8192 + r*128 + ((c ^ (r&15)) << 3)
    // Logical chunks 0..11 hold channels 0..95; 9..11 (ch 72..95) are zero.

    // one-time zero fill of logical chunks 9..11 in BOTH buffers
    for (int z = tid; z < 384; z += 256) {
        int bsel = z / 192;
        int rem  = z - bsel * 192;
        int row  = rem / 3;
        int ch   = 9 + (rem - row * 3);
        *(uintx4*)&s_col[bsel * 8192 + row * 128 + ((ch ^ (row & 15)) << 3)] =
            (uintx4){0u, 0u, 0u, 0u};
    }

    floatx4 acc[4];
#pragma unroll
    for (int t = 0; t < 4; ++t) acc[t] = (floatx4){0.f, 0.f, 0.f, 0.f};

    // build tap kk2's bf16 cols into buffer scW (this lane's own pixel row)
    auto build = [&](int kk2, unsigned short* scW) {
        float offh = s_offh[kk2 * 64 + lane];
        float offw = s_offw[kk2 * 64 + lane];
        float mval = s_maskf[kk2 * 64 + lane];

        float ph = offh + (float)(kk2 / 3) + (float)(ho - 1);
        float pw = offw + (float)(kk2 % 3) + (float)(wo - 1);
        float h0f = floorf(ph), w0f = floorf(pw);
        int h0 = (int)h0f, w0 = (int)w0f;
        int h1 = h0 + 1, w1 = w0 + 1;
        float lh = ph - h0f, lw = pw - w0f;
        float hh = 1.0f - lh, hwp = 1.0f - lw;
        bool okh0 = (unsigned)h0 < 128u, okh1 = (unsigned)h1 < 128u;
        bool okw0 = (unsigned)w0 < 128u, okw1 = (unsigned)w1 < 128u;
        float w00 = (okh0 && okw0) ? hh * hwp * mval : 0.0f;
        float w01 = (okh0 && okw1) ? hh * lw  * mval : 0.0f;
        float w10 = (okh1 && okw0) ? lh * hwp * mval : 0.0f;
        float w11 = (okh1 && okw1) ? lh * lw  * mval : 0.0f;
        int h0c = min(max(h0, 0), 127), h1c = min(max(h1, 0), 127);
        int w0c = min(max(w0, 0), 127), w1c = min(max(w1, 0), 127);
        int o00 = h0c * 128 + w0c, o01 = h0c * 128 + w1c;
        int o10 = h1c * 128 + w0c, o11 = h1c * 128 + w1c;

        unsigned pk[8];
#pragma unroll
        for (int i = 0; i < 8; ++i) {
            const float* pc = inb + (size_t)(wu * 16 + 2 * i) * HW;
            float ca = w00 * pc[o00] + w01 * pc[o01] + w10 * pc[o10] + w11 * pc[o11];
            const float* pd = pc + HW;
            float cb = w00 * pd[o00] + w01 * pd[o01] + w10 * pd[o10] + w11 * pd[o11];
            pk[i] = cvt_pk_bf16(ca, cb);
        }
        unsigned short* rowp = scW + lane * 128;
        const int m = lane & 15;
        *(uintx4*)&rowp[((2 * wu + 0) ^ m) << 3] = (uintx4){pk[0], pk[1], pk[2], pk[3]};
        *(uintx4*)&rowp[((2 * wu + 1) ^ m) << 3] = (uintx4){pk[4], pk[5], pk[6], pk[7]};
        if (wu == 3) {   // logical chunk 8: ch 64,65 real; 66..71 zero
            float y0 = h0c * invH, y1 = h1c * invH;
            float x0 = w0c * invH - 0.5f, x1 = w1c * invH - 0.5f;
            float c64 = (w00 + w01) * y0 + (w10 + w11) * y1;
            float c65 = (w00 + w10) * x0 + (w01 + w11) * x1;
            *(uintx4*)&rowp[(8 ^ m) << 3] =
                (uintx4){cvt_pk_bf16(c64, c65), 0u, 0u, 0u};
        }
    };

    build(0, s_col);
    __syncthreads();

    for (int kk = 0; kk < 9; ++kk) {
        // issue next tap's gathers + writes early (other buffer) so the
        // global-load latency hides under this tap's ds_reads + MFMAs
        if (kk < 8) build(kk + 1, s_col + ((kk + 1) & 1) * 8192);

        const unsigned short* scR = s_col + (kk & 1) * 8192;

        short8 A[3];
#pragma unroll
        for (int ks = 0; ks < 3; ++ks)
            A[ks] = *(const short8*)&wt2[(16 * wu + m15) * 864 + kk * 96 + ks * 32 + quad * 8];

#pragma unroll
        for (int t = 0; t < 4; ++t) {
            const unsigned short* rp = scR + (16 * t + m15) * 128;
#pragma unroll
            for (int ks = 0; ks < 3; ++ks) {
                short8 Bv = *(const short8*)&rp[((ks * 4 + quad) ^ m15) << 3];
                acc[t] = MFMA(A[ks], Bv, acc[t]);
            }
        }
        if (kk < 8) __syncthreads();   // build(kk+1) visible; reads of scR done
    }

    // ---------- Phase B epilogue ----------
    {
        float bs[4];
#pragma unroll
        for (int r = 0; r < 4; ++r) bs[r] = bias[16 * wu + quad * 4 + r];
#pragma unroll
        for (int t = 0; t < 4; ++t) {
            int px = 16 * t + m15;
            size_t pbase = (size_t)ho * 128 + wo0 + px;
#pragma unroll
            for (int r = 0; r < 4; ++r) {
                int o = 16 * wu + quad * 4 + r;
                out[((size_t)b * 64 + o) * HW + pbase] = acc[t][r] + bs[r];
            }
        }
    }
}

// ------------------- fallback (no workspace): fp32 baseline -------------------
__global__ __launch_bounds__(256) void dcn_fb(
    const float* __restrict__ input,
    const float* __restrict__ wmain,
    const float* __restrict__ bias,
    const float* __restrict__ wom,
    const float* __restrict__ b_om,
    float* __restrict__ out)
{
    const int wo = blockIdx.x * 64 + threadIdx.x;
    const int ho = blockIdx.y * 4 + threadIdx.y;
    const int b  = blockIdx.z;
    const int p  = ho * 128 + wo;
    const float invH = 1.0f / 128.0f;
    const float* inb = input + (size_t)b * 64 * HW;

    float om[27];
#pragma unroll
    for (int oc = 0; oc < 27; ++oc) om[oc] = b_om[oc];

    for (int c = 0; c < 64; ++c) {
        const float* pc = inb + c * HW;
        float v[9];
#pragma unroll
        for (int kh = 0; kh < 3; ++kh) {
            int y = ho - 1 + kh;
            bool oky = (unsigned)y < 128u;
#pragma unroll
            for (int kw = 0; kw < 3; ++kw) {
                int x = wo - 1 + kw;
                bool ok = oky && ((unsigned)x < 128u);
                v[kh*3+kw] = ok ? pc[y * 128 + x] : 0.0f;
            }
        }
#pragma unroll
        for (int oc = 0; oc < 27; ++oc)
#pragma unroll
            for (int i = 0; i < 9; ++i)
                om[oc] = fmaf(v[i], wom[oc*594 + c*9 + i], om[oc]);
    }
    {
        float v64[9], v65[9];
#pragma unroll
        for (int kh = 0; kh < 3; ++kh) {
            int y = ho - 1 + kh;
            bool oky = (unsigned)y < 128u;
#pragma unroll
            for (int kw = 0; kw < 3; ++kw) {
                int x = wo - 1 + kw;
                bool ok = oky && ((unsigned)x < 128u);
                v64[kh*3+kw] = ok ? y * invH : 0.0f;
                v65[kh*3+kw] = ok ? (x * invH - 0.5f) : 0.0f;
            }
        }
#pragma unroll
        for (int oc = 0; oc < 27; ++oc)
#pragma unroll
            for (int i = 0; i < 9; ++i) {
                om[oc] = fmaf(v64[i], wom[oc*594 + 64*9 + i], om[oc]);
                om[oc] = fmaf(v65[i], wom[oc*594 + 65*9 + i], om[oc]);
            }
    }

    const float hg = ho * invH;
    const float wg = wo * invH - 0.5f;
    float* out_idx = out + (size_t)8 * 64 * HW;
    float* out_msk = out_idx + (size_t)8 * 18 * HW;
#pragma unroll
    for (int cc = 0; cc < 9; ++cc)
        out_idx[((size_t)b*18 + cc)*HW + p] = hg + (float)(cc/3 - 1) + om[cc];
#pragma unroll
    for (int cc = 9; cc < 18; ++cc)
        out_idx[((size_t)b*18 + cc)*HW + p] = wg + (float)((cc-9)%3 - 1) + om[cc];

    float mk[9];
#pragma unroll
    for (int kk = 0; kk < 9; ++kk) {
        mk[kk] = 1.0f / (1.0f + __expf(-om[18+kk]));
        out_msk[((size_t)b*9 + kk)*HW + p] = mk[kk];
    }

    float acc[64];
#pragma unroll
    for (int o = 0; o < 64; ++o) acc[o] = bias[o];

#pragma unroll
    for (int kk = 0; kk < 9; ++kk) {
        float ph = om[2*kk]   + (float)(kk/3) + (float)(ho - 1);
        float pw = om[2*kk+1] + (float)(kk%3) + (float)(wo - 1);
        float h0f = floorf(ph), w0f = floorf(pw);
        int h0 = (int)h0f, w0 = (int)w0f;
        int h1 = h0 + 1, w1 = w0 + 1;
        float lh = ph - h0f, lw = pw - w0f;
        float hh = 1.0f - lh, hwp = 1.0f - lw;
        float m = mk[kk];
        bool okh0 = (unsigned)h0 < 128u, okh1 = (unsigned)h1 < 128u;
        bool okw0 = (unsigned)w0 < 128u, okw1 = (unsigned)w1 < 128u;
        float w00 = (okh0 && okw0) ? hh*hwp*m : 0.0f;
        float w01 = (okh0 && okw1) ? hh*lw*m  : 0.0f;
        float w10 = (okh1 && okw0) ? lh*hwp*m : 0.0f;
        float w11 = (okh1 && okw1) ? lh*lw*m  : 0.0f;
        int h0c = min(max(h0, 0), 127), h1c = min(max(h1, 0), 127);
        int w0c = min(max(w0, 0), 127), w1c = min(max(w1, 0), 127);
        int o00 = h0c*128 + w0c, o01 = h0c*128 + w1c;
        int o10 = h1c*128 + w0c, o11 = h1c*128 + w1c;

        for (int c = 0; c < 64; ++c) {
            const float* pc = inb + c * HW;
            float col = w00*pc[o00] + w01*pc[o01] + w10*pc[o10] + w11*pc[o11];
#pragma unroll
            for (int o = 0; o < 64; ++o)
                acc[o] = fmaf(col, wmain[o*594 + c*9 + kk], acc[o]);
        }
        {
            float y0 = h0c * invH, y1 = h1c * invH;
            float x0 = w0c * invH - 0.5f, x1 = w1c * invH - 0.5f;
            float col64 = (w00 + w01)*y0 + (w10 + w11)*y1;
            float col65 = (w00 + w10)*x0 + (w01 + w11)*x1;
#pragma unroll
            for (int o = 0; o < 64; ++o) {
                acc[o] = fmaf(col64, wmain[o*594 + 64*9 + kk], acc[o]);
                acc[o] = fmaf(col65, wmain[o*594 + 65*9 + kk], acc[o]);
            }
        }
    }

#pragma unroll
    for (int o = 0; o < 64; ++o)
        out[((size_t)b*64 + o)*HW + p] = acc[o];
}

extern "C" void kernel_launch(void* const* d_in, const int* in_sizes, int n_in,
                              void* d_out, int out_size, void* d_ws, size_t ws_size,
                              hipStream_t stream)
{
    const float* input  = (const float*)d_in[0];
    const float* weight = (const float*)d_in[1];
    const float* bias   = (const float*)d_in[2];
    const float* w_om   = (const float*)d_in[3];
    const float* b_om   = (const float*)d_in[4];
    float* out = (float*)d_out;

    if (ws_size >= (size_t)WS_NEED) {
        unsigned short* wt2 = (unsigned short*)d_ws;
        float* wmt = (float*)((char*)d_ws + WT2_BYTES);
        int total = WT2_ELEMS + WMT_ELEMS;
        prep_w<<<(total + 255) / 256, 256, 0, stream>>>(weight, w_om, wt2, wmt);
        dim3 grid(2, 128, 8);
        dcn_hybrid3<<<grid, dim3(256, 1, 1), 0, stream>>>(input, wt2, bias, wmt, b_om, out);
    } else {
        dim3 grid(2, 32, 8);
        dcn_fb<<<grid, dim3(64, 4, 1), 0, stream>>>(input, weight, bias, w_om, b_om, out);
    }
}

// Round 2
// 323.491 us; speedup vs baseline: 1.0312x; 1.0312x over previous
//
#include <hip/hip_runtime.h>
#include <math.h>

#define HW (128*128)

typedef short short8 __attribute__((ext_vector_type(8)));
typedef float floatx4 __attribute__((ext_vector_type(4)));
typedef unsigned int uintx4 __attribute__((ext_vector_type(4)));

#define MFMA(a,b,c) __builtin_amdgcn_mfma_f32_16x16x32_bf16((a),(b),(c),0,0,0)

// workspace: [wt2: bf16 main weight 64x864][wmt: fp32 offset weight 594*27]
#define WT2_ELEMS  (64*864)          // [o][kk*96 + c], zero for c>=66
#define WT2_BYTES  (WT2_ELEMS*2)
#define WMT_ELEMS  (594*27)          // [(c*9+j)*27 + oc]
#define WS_NEED    (WT2_BYTES + WMT_ELEMS*4)

static __device__ __forceinline__ unsigned short f2bf(float x) {
    unsigned u = __float_as_uint(x);
    unsigned r = u + 0x7FFFu + ((u >> 16) & 1u);
    return (unsigned short)(r >> 16);
}

// pack 2 fp32 -> 2 bf16 (RNE) in one instruction; low16 = lo, high16 = hi
static __device__ __forceinline__ unsigned cvt_pk_bf16(float lo, float hi) {
    unsigned r;
    asm("v_cvt_pk_bf16_f32 %0, %1, %2" : "=v"(r) : "v"(lo), "v"(hi));
    return r;
}

__global__ __launch_bounds__(256) void prep_w(
    const float* __restrict__ weight, const float* __restrict__ w_om,
    unsigned short* __restrict__ wt2, float* __restrict__ wmt)
{
    int t = blockIdx.x * 256 + threadIdx.x;
    if (t < WT2_ELEMS) {
        int o = t / 864, k = t % 864;
        int kk = k / 96, c = k % 96;
        float v = (c < 66) ? weight[o * 594 + c * 9 + kk] : 0.0f;
        wt2[t] = f2bf(v);
    } else if (t < WT2_ELEMS + WMT_ELEMS) {
        int t2 = t - WT2_ELEMS;
        int oc = t2 % 27, ck = t2 / 27;
        wmt[t2] = w_om[oc * 594 + ck];
    }
}

// Phase A: fp32 VALU offset conv (verified path, unchanged).
// Phase B: cols as bf16 in LDS, XOR-swizzled 256B rows, double-buffered,
//          one barrier per tap; build(kk+1) overlaps MFMA(kk).
// Round 2 change: XCD-pinning block remap. Linear dispatch id L is assigned
// round-robin to XCDs (xcd = L % 8); map batch = L & 7 so each XCD works a
// single batch (4.2 MB input, fits its private 4 MB L2), with ho ascending
// within the XCD so ho and ho+1 blocks (sharing 2/3 input rows) are
// temporally adjacent on the same L2. Targets the measured 16x over-fetch
// (FETCH_SIZE 268 MB vs 16.8 MB unique input).
__global__ __launch_bounds__(256, 4) void dcn_hybrid4(
    const float* __restrict__ input,
    const unsigned short* __restrict__ wt2,
    const float* __restrict__ bias,
    const float* __restrict__ wmt,
    const float* __restrict__ b_om,
    float* __restrict__ out)
{
    // 2 buffers x 64 rows x 128 ushort (16 chunks of 8 bf16, swizzled) = 32 KB.
    // Aliases Phase-A s_red (6912 floats = 27648 B < 32768 B).
    __shared__ __align__(16) unsigned short s_col[2 * 64 * 128];
    __shared__ float s_offh[9 * 64], s_offw[9 * 64], s_maskf[9 * 64];
    float* s_red = (float*)s_col;

    const int tid  = threadIdx.x;
    const int lane = tid & 63;
    const int w    = tid >> 6;
    const int wu   = __builtin_amdgcn_readfirstlane(w);
    const int m15  = lane & 15;
    const int quad = lane >> 4;

    // ---- XCD-pinning remap (pure permutation of block->work assignment)
    const int L   = blockIdx.x + 2 * (blockIdx.y + 128 * blockIdx.z);
    const int b   = L & 7;           // batch == XCD (assuming xcd = L % 8)
    const int r   = L >> 3;          // 0..255 within this XCD
    const int ho  = r >> 1;          // ascending rows per XCD
    const int wo0 = (r & 1) * 64;

    const int wo  = wo0 + lane;
    const int p   = ho * 128 + wo;
    const float invH = 1.0f / 128.0f;

    const float* inb = input + (size_t)b * 64 * HW;

    // ---- 9 fixed-tap addresses / validity for pixel (ho, wo)
    int   a9[9];
    float okf[9], vy[9], vx[9];
#pragma unroll
    for (int j = 0; j < 9; ++j) {
        int y = ho - 1 + j / 3;
        int x = wo - 1 + j % 3;
        bool ok = ((unsigned)y < 128u) && ((unsigned)x < 128u);
        int yc = min(max(y, 0), 127), xc = min(max(x, 0), 127);
        a9[j]  = yc * 128 + xc;
        okf[j] = ok ? 1.0f : 0.0f;
        vy[j]  = ok ? y * invH : 0.0f;
        vx[j]  = ok ? (x * invH - 0.5f) : 0.0f;
    }

    const int nc = (wu < 2) ? 17 : 16;     // channels per wave: c = wu + 4*i

    // ---------------- Phase A: fp32 partial offset conv ----------------
    float om_part[27];
#pragma unroll
    for (int oc = 0; oc < 27; ++oc) om_part[oc] = 0.0f;

    for (int i = 0; i < nc; ++i) {
        int c = wu + 4 * i;
        float v[9];
        if (c < 64) {
            const float* pc = inb + c * HW;
#pragma unroll
            for (int j = 0; j < 9; ++j) v[j] = pc[a9[j]] * okf[j];
        } else if (c == 64) {
#pragma unroll
            for (int j = 0; j < 9; ++j) v[j] = vy[j];
        } else {
#pragma unroll
            for (int j = 0; j < 9; ++j) v[j] = vx[j];
        }
#pragma unroll
        for (int j = 0; j < 9; ++j) {
            const float* wp = wmt + (c * 9 + j) * 27;
#pragma unroll
            for (int oc = 0; oc < 27; ++oc)
                om_part[oc] = fmaf(v[j], wp[oc], om_part[oc]);
        }
    }
#pragma unroll
    for (int oc = 0; oc < 27; ++oc)
        s_red[(w * 27 + oc) * 64 + lane] = om_part[oc];
    __syncthreads();

    // ---- 4-way reduce + idx/mask epilogue + fp32 offsets/mask into LDS
    {
        float* out_idx = out + (size_t)8 * 64 * HW;
        float* out_msk = out_idx + (size_t)8 * 18 * HW;
        const float hg = ho * invH;
        const float wg = wo * invH - 0.5f;
        int oc0 = wu * 7;
        int noc = (wu == 3) ? 6 : 7;
        for (int t = 0; t < noc; ++t) {
            int oc = oc0 + t;
            float s = b_om[oc]
                    + s_red[(0 * 27 + oc) * 64 + lane]
                    + s_red[(1 * 27 + oc) * 64 + lane]
                    + s_red[(2 * 27 + oc) * 64 + lane]
                    + s_red[(3 * 27 + oc) * 64 + lane];
            if (oc < 9) {
                out_idx[((size_t)b * 18 + oc) * HW + p] = hg + (float)(oc / 3 - 1) + s;
                if (oc & 1) s_offw[(oc >> 1) * 64 + lane] = s;
                else        s_offh[(oc >> 1) * 64 + lane] = s;
            } else if (oc < 18) {
                out_idx[((size_t)b * 18 + oc) * HW + p] = wg + (float)((oc - 9) % 3 - 1) + s;
                if (oc & 1) s_offw[(oc >> 1) * 64 + lane] = s;
                else        s_offh[(oc >> 1) * 64 + lane] = s;
            } else {
                float mkv = 1.0f / (1.0f + __expf(-s));
                out_msk[((size_t)b * 9 + (oc - 18)) * HW + p] = mkv;
                s_maskf[(oc - 18) * 64 + lane] = mkv;
            }
        }
    }
    __syncthreads();   // s_red reads done; offsets/mask ready; s_col usable

    // ---------------- Phase B: bf16 swizzled cols + MFMA ----------------
    // Layout: buffer[buf] row r (pixel), logical chunk c (8 bf16 = 8 channels):
    //   ushort index = buf*8192 + r*128 + ((c ^ (r&15)) << 3)
    // Logical chunks 0..11 hold channels 0..95; 9..11 (ch 72..95) are zero.

    // one-time zero fill of logical chunks 9..11 in BOTH buffers
    for (int z = tid; z < 384; z += 256) {
        int bsel = z / 192;
        int rem  = z - bsel * 192;
        int row  = rem / 3;
        int ch   = 9 + (rem - row * 3);
        *(uintx4*)&s_col[bsel * 8192 + row * 128 + ((ch ^ (row & 15)) << 3)] =
            (uintx4){0u, 0u, 0u, 0u};
    }

    floatx4 acc[4];
#pragma unroll
    for (int t = 0; t < 4; ++t) acc[t] = (floatx4){0.f, 0.f, 0.f, 0.f};

    // build tap kk2's bf16 cols into buffer scW (this lane's own pixel row)
    auto build = [&](int kk2, unsigned short* scW) {
        float offh = s_offh[kk2 * 64 + lane];
        float offw = s_offw[kk2 * 64 + lane];
        float mval = s_maskf[kk2 * 64 + lane];

        float ph = offh + (float)(kk2 / 3) + (float)(ho - 1);
        float pw = offw + (float)(kk2 % 3) + (float)(wo - 1);
        float h0f = floorf(ph), w0f = floorf(pw);
        int h0 = (int)h0f, w0 = (int)w0f;
        int h1 = h0 + 1, w1 = w0 + 1;
        float lh = ph - h0f, lw = pw - w0f;
        float hh = 1.0f - lh, hwp = 1.0f - lw;
        bool okh0 = (unsigned)h0 < 128u, okh1 = (unsigned)h1 < 128u;
        bool okw0 = (unsigned)w0 < 128u, okw1 = (unsigned)w1 < 128u;
        float w00 = (okh0 && okw0) ? hh * hwp * mval : 0.0f;
        float w01 = (okh0 && okw1) ? hh * lw  * mval : 0.0f;
        float w10 = (okh1 && okw0) ? lh * hwp * mval : 0.0f;
        float w11 = (okh1 && okw1) ? lh * lw  * mval : 0.0f;
        int h0c = min(max(h0, 0), 127), h1c = min(max(h1, 0), 127);
        int w0c = min(max(w0, 0), 127), w1c = min(max(w1, 0), 127);
        int o00 = h0c * 128 + w0c, o01 = h0c * 128 + w1c;
        int o10 = h1c * 128 + w0c, o11 = h1c * 128 + w1c;

        unsigned pk[8];
#pragma unroll
        for (int i = 0; i < 8; ++i) {
            const float* pc = inb + (size_t)(wu * 16 + 2 * i) * HW;
            float ca = w00 * pc[o00] + w01 * pc[o01] + w10 * pc[o10] + w11 * pc[o11];
            const float* pd = pc + HW;
            float cb = w00 * pd[o00] + w01 * pd[o01] + w10 * pd[o10] + w11 * pd[o11];
            pk[i] = cvt_pk_bf16(ca, cb);
        }
        unsigned short* rowp = scW + lane * 128;
        const int m = lane & 15;
        *(uintx4*)&rowp[((2 * wu + 0) ^ m) << 3] = (uintx4){pk[0], pk[1], pk[2], pk[3]};
        *(uintx4*)&rowp[((2 * wu + 1) ^ m) << 3] = (uintx4){pk[4], pk[5], pk[6], pk[7]};
        if (wu == 3) {   // logical chunk 8: ch 64,65 real; 66..71 zero
            float y0 = h0c * invH, y1 = h1c * invH;
            float x0 = w0c * invH - 0.5f, x1 = w1c * invH - 0.5f;
            float c64 = (w00 + w01) * y0 + (w10 + w11) * y1;
            float c65 = (w00 + w10) * x0 + (w01 + w11) * x1;
            *(uintx4*)&rowp[(8 ^ m) << 3] =
                (uintx4){cvt_pk_bf16(c64, c65), 0u, 0u, 0u};
        }
    };

    build(0, s_col);
    __syncthreads();

    for (int kk = 0; kk < 9; ++kk) {
        // issue next tap's gathers + writes early (other buffer) so the
        // global-load latency hides under this tap's ds_reads + MFMAs
        if (kk < 8) build(kk + 1, s_col + ((kk + 1) & 1) * 8192);

        const unsigned short* scR = s_col + (kk & 1) * 8192;

        short8 A[3];
#pragma unroll
        for (int ks = 0; ks < 3; ++ks)
            A[ks] = *(const short8*)&wt2[(16 * wu + m15) * 864 + kk * 96 + ks * 32 + quad * 8];

#pragma unroll
        for (int t = 0; t < 4; ++t) {
            const unsigned short* rp = scR + (16 * t + m15) * 128;
#pragma unroll
            for (int ks = 0; ks < 3; ++ks) {
                short8 Bv = *(const short8*)&rp[((ks * 4 + quad) ^ m15) << 3];
                acc[t] = MFMA(A[ks], Bv, acc[t]);
            }
        }
        if (kk < 8) __syncthreads();   // build(kk+1) visible; reads of scR done
    }

    // ---------- Phase B epilogue ----------
    {
        float bs[4];
#pragma unroll
        for (int r2 = 0; r2 < 4; ++r2) bs[r2] = bias[16 * wu + quad * 4 + r2];
#pragma unroll
        for (int t = 0; t < 4; ++t) {
            int px = 16 * t + m15;
            size_t pbase = (size_t)ho * 128 + wo0 + px;
#pragma unroll
            for (int r2 = 0; r2 < 4; ++r2) {
                int o = 16 * wu + quad * 4 + r2;
                out[((size_t)b * 64 + o) * HW + pbase] = acc[t][r2] + bs[r2];
            }
        }
    }
}

// ------------------- fallback (no workspace): fp32 baseline -------------------
__global__ __launch_bounds__(256) void dcn_fb(
    const float* __restrict__ input,
    const float* __restrict__ wmain,
    const float* __restrict__ bias,
    const float* __restrict__ wom,
    const float* __restrict__ b_om,
    float* __restrict__ out)
{
    const int wo = blockIdx.x * 64 + threadIdx.x;
    const int ho = blockIdx.y * 4 + threadIdx.y;
    const int b  = blockIdx.z;
    const int p  = ho * 128 + wo;
    const float invH = 1.0f / 128.0f;
    const float* inb = input + (size_t)b * 64 * HW;

    float om[27];
#pragma unroll
    for (int oc = 0; oc < 27; ++oc) om[oc] = b_om[oc];

    for (int c = 0; c < 64; ++c) {
        const float* pc = inb + c * HW;
        float v[9];
#pragma unroll
        for (int kh = 0; kh < 3; ++kh) {
            int y = ho - 1 + kh;
            bool oky = (unsigned)y < 128u;
#pragma unroll
            for (int kw = 0; kw < 3; ++kw) {
                int x = wo - 1 + kw;
                bool ok = oky && ((unsigned)x < 128u);
                v[kh*3+kw] = ok ? pc[y * 128 + x] : 0.0f;
            }
        }
#pragma unroll
        for (int oc = 0; oc < 27; ++oc)
#pragma unroll
            for (int i = 0; i < 9; ++i)
                om[oc] = fmaf(v[i], wom[oc*594 + c*9 + i], om[oc]);
    }
    {
        float v64[9], v65[9];
#pragma unroll
        for (int kh = 0; kh < 3; ++kh) {
            int y = ho - 1 + kh;
            bool oky = (unsigned)y < 128u;
#pragma unroll
            for (int kw = 0; kw < 3; ++kw) {
                int x = wo - 1 + kw;
                bool ok = oky && ((unsigned)x < 128u);
                v64[kh*3+kw] = ok ? y * invH : 0.0f;
                v65[kh*3+kw] = ok ? (x * invH - 0.5f) : 0.0f;
            }
        }
#pragma unroll
        for (int oc = 0; oc < 27; ++oc)
#pragma unroll
            for (int i = 0; i < 9; ++i) {
                om[oc] = fmaf(v64[i], wom[oc*594 + 64*9 + i], om[oc]);
                om[oc] = fmaf(v65[i], wom[oc*594 + 65*9 + i], om[oc]);
            }
    }

    const float hg = ho * invH;
    const float wg = wo * invH - 0.5f;
    float* out_idx = out + (size_t)8 * 64 * HW;
    float* out_msk = out_idx + (size_t)8 * 18 * HW;
#pragma unroll
    for (int cc = 0; cc < 9; ++cc)
        out_idx[((size_t)b*18 + cc)*HW + p] = hg + (float)(cc/3 - 1) + om[cc];
#pragma unroll
    for (int cc = 9; cc < 18; ++cc)
        out_idx[((size_t)b*18 + cc)*HW + p] = wg + (float)((cc-9)%3 - 1) + om[cc];

    float mk[9];
#pragma unroll
    for (int kk = 0; kk < 9; ++kk) {
        mk[kk] = 1.0f / (1.0f + __expf(-om[18+kk]));
        out_msk[((size_t)b*9 + kk)*HW + p] = mk[kk];
    }

    float acc[64];
#pragma unroll
    for (int o = 0; o < 64; ++o) acc[o] = bias[o];

#pragma unroll
    for (int kk = 0; kk < 9; ++kk) {
        float ph = om[2*kk]   + (float)(kk/3) + (float)(ho - 1);
        float pw = om[2*kk+1] + (float)(kk%3) + (float)(wo - 1);
        float h0f = floorf(ph), w0f = floorf(pw);
        int h0 = (int)h0f, w0 = (int)w0f;
        int h1 = h0 + 1, w1 = w0 + 1;
        float lh = ph - h0f, lw = pw - w0f;
        float hh = 1.0f - lh, hwp = 1.0f - lw;
        float m = mk[kk];
        bool okh0 = (unsigned)h0 < 128u, okh1 = (unsigned)h1 < 128u;
        bool okw0 = (unsigned)w0 < 128u, okw1 = (unsigned)w1 < 128u;
        float w00 = (okh0 && okw0) ? hh*hwp*m : 0.0f;
        float w01 = (okh0 && okw1) ? hh*lw*m  : 0.0f;
        float w10 = (okh1 && okw0) ? lh*hwp*m : 0.0f;
        float w11 = (okh1 && okw1) ? lh*lw*m  : 0.0f;
        int h0c = min(max(h0, 0), 127), h1c = min(max(h1, 0), 127);
        int w0c = min(max(w0, 0), 127), w1c = min(max(w1, 0), 127);
        int o00 = h0c*128 + w0c, o01 = h0c*128 + w1c;
        int o10 = h1c*128 + w0c, o11 = h1c*128 + w1c;

        for (int c = 0; c < 64; ++c) {
            const float* pc = inb + c * HW;
            float col = w00*pc[o00] + w01*pc[o01] + w10*pc[o10] + w11*pc[o11];
#pragma unroll
            for (int o = 0; o < 64; ++o)
                acc[o] = fmaf(col, wmain[o*594 + c*9 + kk], acc[o]);
        }
        {
            float y0 = h0c * invH, y1 = h1c * invH;
            float x0 = w0c * invH - 0.5f, x1 = w1c * invH - 0.5f;
            float col64 = (w00 + w01)*y0 + (w10 + w11)*y1;
            float col65 = (w00 + w10)*x0 + (w01 + w11)*x1;
#pragma unroll
            for (int o = 0; o < 64; ++o) {
                acc[o] = fmaf(col64, wmain[o*594 + 64*9 + kk], acc[o]);
                acc[o] = fmaf(col65, wmain[o*594 + 65*9 + kk], acc[o]);
            }
        }
    }

#pragma unroll
    for (int o = 0; o < 64; ++o)
        out[((size_t)b*64 + o)*HW + p] = acc[o];
}

extern "C" void kernel_launch(void* const* d_in, const int* in_sizes, int n_in,
                              void* d_out, int out_size, void* d_ws, size_t ws_size,
                              hipStream_t stream)
{
    const float* input  = (const float*)d_in[0];
    const float* weight = (const float*)d_in[1];
    const float* bias   = (const float*)d_in[2];
    const float* w_om   = (const float*)d_in[3];
    const float* b_om   = (const float*)d_in[4];
    float* out = (float*)d_out;

    if (ws_size >= (size_t)WS_NEED) {
        unsigned short* wt2 = (unsigned short*)d_ws;
        float* wmt = (float*)((char*)d_ws + WT2_BYTES);
        int total = WT2_ELEMS + WMT_ELEMS;
        prep_w<<<(total + 255) / 256, 256, 0, stream>>>(weight, w_om, wt2, wmt);
        dim3 grid(2, 128, 8);
        dcn_hybrid4<<<grid, dim3(256, 1, 1), 0, stream>>>(input, wt2, bias, wmt, b_om, out);
    } else {
        dim3 grid(2, 32, 8);
        dcn_fb<<<grid, dim3(64, 4, 1), 0, stream>>>(input, weight, bias, w_om, b_om, out);
    }
}

// Round 3
// 317.805 us; speedup vs baseline: 1.0497x; 1.0179x over previous
//
#include <hip/hip_runtime.h>
#include <math.h>

#define HW (128*128)

typedef short short8 __attribute__((ext_vector_type(8)));
typedef float floatx4 __attribute__((ext_vector_type(4)));
typedef unsigned int uintx4 __attribute__((ext_vector_type(4)));

#define MFMA(a,b,c) __builtin_amdgcn_mfma_f32_16x16x32_bf16((a),(b),(c),0,0,0)

// workspace: [wt2: bf16 main weight 64x864][wmt: fp32 offset weight 594*27]
#define WT2_ELEMS  (64*864)          // [o][kk*96 + c], zero for c>=66
#define WT2_BYTES  (WT2_ELEMS*2)
#define WMT_ELEMS  (594*27)          // [(c*9+j)*27 + oc]
#define WS_NEED    (WT2_BYTES + WMT_ELEMS*4)

static __device__ __forceinline__ unsigned short f2bf(float x) {
    unsigned u = __float_as_uint(x);
    unsigned r = u + 0x7FFFu + ((u >> 16) & 1u);
    return (unsigned short)(r >> 16);
}

// pack 2 fp32 -> 2 bf16 (RNE) in one instruction; low16 = lo, high16 = hi
static __device__ __forceinline__ unsigned cvt_pk_bf16(float lo, float hi) {
    unsigned r;
    asm("v_cvt_pk_bf16_f32 %0, %1, %2" : "=v"(r) : "v"(lo), "v"(hi));
    return r;
}

__global__ __launch_bounds__(256) void prep_w(
    const float* __restrict__ weight, const float* __restrict__ w_om,
    unsigned short* __restrict__ wt2, float* __restrict__ wmt)
{
    int t = blockIdx.x * 256 + threadIdx.x;
    if (t < WT2_ELEMS) {
        int o = t / 864, k = t % 864;
        int kk = k / 96, c = k % 96;
        float v = (c < 66) ? weight[o * 594 + c * 9 + kk] : 0.0f;
        wt2[t] = f2bf(v);
    } else if (t < WT2_ELEMS + WMT_ELEMS) {
        int t2 = t - WT2_ELEMS;
        int oc = t2 % 27, ck = t2 / 27;
        wmt[t2] = w_om[oc * 594 + ck];
    }
}

// Round 2: XCD-pinning block remap (verified: FETCH 268MB -> 18.5MB).
// Round 3: deep MLP. Tap loop restructured as
//     issue 64 gather loads for tap kk+1 (regs g[64])
//  -> MFMA block for tap kk (ds_read other buffer)
//  -> finish: FMA/cvt/LDS-write tap kk+1
//  -> barrier
// so one full MFMA phase covers the L2 latency of the 64 loads, with
// in-flight depth 64 instead of compiler's ~8 at 60 VGPRs. Phase A gets an
// explicit 1-channel (9-load) lookahead under its 486-cycle FMA block.
__global__ __launch_bounds__(256, 4) void dcn_hybrid5(
    const float* __restrict__ input,
    const unsigned short* __restrict__ wt2,
    const float* __restrict__ bias,
    const float* __restrict__ wmt,
    const float* __restrict__ b_om,
    float* __restrict__ out)
{
    // 2 buffers x 64 rows x 128 ushort (16 chunks of 8 bf16, swizzled) = 32 KB.
    // Aliases Phase-A s_red (6912 floats = 27648 B < 32768 B).
    __shared__ __align__(16) unsigned short s_col[2 * 64 * 128];
    __shared__ float s_offh[9 * 64], s_offw[9 * 64], s_maskf[9 * 64];
    float* s_red = (float*)s_col;

    const int tid  = threadIdx.x;
    const int lane = tid & 63;
    const int w    = tid >> 6;
    const int wu   = __builtin_amdgcn_readfirstlane(w);
    const int m15  = lane & 15;
    const int quad = lane >> 4;

    // ---- XCD-pinning remap (pure permutation of block->work assignment)
    const int L   = blockIdx.x + 2 * (blockIdx.y + 128 * blockIdx.z);
    const int b   = L & 7;           // batch == XCD (xcd = L % 8)
    const int r   = L >> 3;          // 0..255 within this XCD
    const int ho  = r >> 1;          // ascending rows per XCD
    const int wo0 = (r & 1) * 64;

    const int wo  = wo0 + lane;
    const int p   = ho * 128 + wo;
    const float invH = 1.0f / 128.0f;

    const float* inb = input + (size_t)b * 64 * HW;

    // ---- 9 fixed-tap addresses / validity for pixel (ho, wo)
    int   a9[9];
    float okf[9], vy[9], vx[9];
#pragma unroll
    for (int j = 0; j < 9; ++j) {
        int y = ho - 1 + j / 3;
        int x = wo - 1 + j % 3;
        bool ok = ((unsigned)y < 128u) && ((unsigned)x < 128u);
        int yc = min(max(y, 0), 127), xc = min(max(x, 0), 127);
        a9[j]  = yc * 128 + xc;
        okf[j] = ok ? 1.0f : 0.0f;
        vy[j]  = ok ? y * invH : 0.0f;
        vx[j]  = ok ? (x * invH - 0.5f) : 0.0f;
    }

    const int nc = (wu < 2) ? 17 : 16;     // channels per wave: c = wu + 4*i

    // ---------------- Phase A: fp32 partial offset conv ----------------
    float om_part[27];
#pragma unroll
    for (int oc = 0; oc < 27; ++oc) om_part[oc] = 0.0f;

    {
        float va[9], vb[9];
        {   // preload first channel (c = wu < 64 always)
            const float* pc = inb + wu * HW;
#pragma unroll
            for (int j = 0; j < 9; ++j) va[j] = pc[a9[j]] * okf[j];
        }
        for (int i = 0; i < nc; ++i) {
            int c = wu + 4 * i;
            if (i + 1 < nc) {          // issue next channel's loads early
                int cn = c + 4;
                if (cn < 64) {
                    const float* pc = inb + cn * HW;
#pragma unroll
                    for (int j = 0; j < 9; ++j) vb[j] = pc[a9[j]] * okf[j];
                } else if (cn == 64) {
#pragma unroll
                    for (int j = 0; j < 9; ++j) vb[j] = vy[j];
                } else {
#pragma unroll
                    for (int j = 0; j < 9; ++j) vb[j] = vx[j];
                }
            }
#pragma unroll
            for (int j = 0; j < 9; ++j) {
                const float* wp = wmt + (c * 9 + j) * 27;
#pragma unroll
                for (int oc = 0; oc < 27; ++oc)
                    om_part[oc] = fmaf(va[j], wp[oc], om_part[oc]);
            }
#pragma unroll
            for (int j = 0; j < 9; ++j) va[j] = vb[j];
        }
    }
#pragma unroll
    for (int oc = 0; oc < 27; ++oc)
        s_red[(w * 27 + oc) * 64 + lane] = om_part[oc];
    __syncthreads();

    // ---- 4-way reduce + idx/mask epilogue + fp32 offsets/mask into LDS
    {
        float* out_idx = out + (size_t)8 * 64 * HW;
        float* out_msk = out_idx + (size_t)8 * 18 * HW;
        const float hg = ho * invH;
        const float wg = wo * invH - 0.5f;
        int oc0 = wu * 7;
        int noc = (wu == 3) ? 6 : 7;
        for (int t = 0; t < noc; ++t) {
            int oc = oc0 + t;
            float s = b_om[oc]
                    + s_red[(0 * 27 + oc) * 64 + lane]
                    + s_red[(1 * 27 + oc) * 64 + lane]
                    + s_red[(2 * 27 + oc) * 64 + lane]
                    + s_red[(3 * 27 + oc) * 64 + lane];
            if (oc < 9) {
                out_idx[((size_t)b * 18 + oc) * HW + p] = hg + (float)(oc / 3 - 1) + s;
                if (oc & 1) s_offw[(oc >> 1) * 64 + lane] = s;
                else        s_offh[(oc >> 1) * 64 + lane] = s;
            } else if (oc < 18) {
                out_idx[((size_t)b * 18 + oc) * HW + p] = wg + (float)((oc - 9) % 3 - 1) + s;
                if (oc & 1) s_offw[(oc >> 1) * 64 + lane] = s;
                else        s_offh[(oc >> 1) * 64 + lane] = s;
            } else {
                float mkv = 1.0f / (1.0f + __expf(-s));
                out_msk[((size_t)b * 9 + (oc - 18)) * HW + p] = mkv;
                s_maskf[(oc - 18) * 64 + lane] = mkv;
            }
        }
    }
    __syncthreads();   // s_red reads done; offsets/mask ready; s_col usable

    // ---------------- Phase B: bf16 swizzled cols + MFMA ----------------
    // Layout: buffer[buf] row r (pixel), logical chunk c (8 bf16 = 8 channels):
    //   ushort index = buf*8192 + r*128 + ((c ^ (r&15)) << 3)
    // Logical chunks 0..11 hold channels 0..95; 9..11 (ch 72..95) are zero.

    // one-time zero fill of logical chunks 9..11 in BOTH buffers
    for (int z = tid; z < 384; z += 256) {
        int bsel = z / 192;
        int rem  = z - bsel * 192;
        int row  = rem / 3;
        int ch   = 9 + (rem - row * 3);
        *(uintx4*)&s_col[bsel * 8192 + row * 128 + ((ch ^ (row & 15)) << 3)] =
            (uintx4){0u, 0u, 0u, 0u};
    }

    floatx4 acc[4];
#pragma unroll
    for (int t = 0; t < 4; ++t) acc[t] = (floatx4){0.f, 0.f, 0.f, 0.f};

    // ---- per-tap gather state (registers, one tap in flight)
    float w00, w01, w10, w11, y0v, y1v, x0v, x1v;
    int   o00, o01, o10, o11;
    float g[64];

    // addressing + corner weights for tap kk2 (reads LDS offsets)
    auto ctx = [&](int kk2) {
        float offh = s_offh[kk2 * 64 + lane];
        float offw = s_offw[kk2 * 64 + lane];
        float mval = s_maskf[kk2 * 64 + lane];

        float ph = offh + (float)(kk2 / 3) + (float)(ho - 1);
        float pw = offw + (float)(kk2 % 3) + (float)(wo - 1);
        float h0f = floorf(ph), w0f = floorf(pw);
        int h0 = (int)h0f, w0 = (int)w0f;
        int h1 = h0 + 1, w1 = w0 + 1;
        float lh = ph - h0f, lw = pw - w0f;
        float hh = 1.0f - lh, hwp = 1.0f - lw;
        bool okh0 = (unsigned)h0 < 128u, okh1 = (unsigned)h1 < 128u;
        bool okw0 = (unsigned)w0 < 128u, okw1 = (unsigned)w1 < 128u;
        w00 = (okh0 && okw0) ? hh * hwp * mval : 0.0f;
        w01 = (okh0 && okw1) ? hh * lw  * mval : 0.0f;
        w10 = (okh1 && okw0) ? lh * hwp * mval : 0.0f;
        w11 = (okh1 && okw1) ? lh * lw  * mval : 0.0f;
        int h0c = min(max(h0, 0), 127), h1c = min(max(h1, 0), 127);
        int w0c = min(max(w0, 0), 127), w1c = min(max(w1, 0), 127);
        o00 = h0c * 128 + w0c; o01 = h0c * 128 + w1c;
        o10 = h1c * 128 + w0c; o11 = h1c * 128 + w1c;
        y0v = h0c * invH; y1v = h1c * invH;
        x0v = w0c * invH - 0.5f; x1v = w1c * invH - 0.5f;
    };

    // issue all 64 gather loads for the current ctx into g[] (in-flight depth 64)
    auto issue = [&]() {
        const float* base = inb + (size_t)(wu * 16) * HW;
#pragma unroll
        for (int i = 0; i < 8; ++i) {
            const float* pc = base + (size_t)(2 * i) * HW;
            g[i * 8 + 0] = pc[o00]; g[i * 8 + 1] = pc[o01];
            g[i * 8 + 2] = pc[o10]; g[i * 8 + 3] = pc[o11];
            const float* pd = pc + HW;
            g[i * 8 + 4] = pd[o00]; g[i * 8 + 5] = pd[o01];
            g[i * 8 + 6] = pd[o10]; g[i * 8 + 7] = pd[o11];
        }
    };

    // consume g[]: bilinear FMA, cvt to bf16, swizzled LDS write
    auto finishW = [&](unsigned short* scW) {
        unsigned pk[8];
#pragma unroll
        for (int i = 0; i < 8; ++i) {
            float ca = w00 * g[i * 8 + 0] + w01 * g[i * 8 + 1]
                     + w10 * g[i * 8 + 2] + w11 * g[i * 8 + 3];
            float cb = w00 * g[i * 8 + 4] + w01 * g[i * 8 + 5]
                     + w10 * g[i * 8 + 6] + w11 * g[i * 8 + 7];
            pk[i] = cvt_pk_bf16(ca, cb);
        }
        unsigned short* rowp = scW + lane * 128;
        const int m = lane & 15;
        *(uintx4*)&rowp[((2 * wu + 0) ^ m) << 3] = (uintx4){pk[0], pk[1], pk[2], pk[3]};
        *(uintx4*)&rowp[((2 * wu + 1) ^ m) << 3] = (uintx4){pk[4], pk[5], pk[6], pk[7]};
        if (wu == 3) {   // logical chunk 8: ch 64,65 real; 66..71 zero
            float c64 = (w00 + w01) * y0v + (w10 + w11) * y1v;
            float c65 = (w00 + w10) * x0v + (w01 + w11) * x1v;
            *(uintx4*)&rowp[(8 ^ m) << 3] =
                (uintx4){cvt_pk_bf16(c64, c65), 0u, 0u, 0u};
        }
    };

    // prologue: tap 0 into buffer 0
    ctx(0); issue(); finishW(s_col);
    __syncthreads();

    for (int kk = 0; kk < 9; ++kk) {
        // issue next tap's 64 loads BEFORE this tap's MFMA block: the MFMA
        // phase (~400+ cy of ds_read+MFMA) covers the L2 latency.
        if (kk < 8) { ctx(kk + 1); issue(); }

        const unsigned short* scR = s_col + (kk & 1) * 8192;

        short8 A[3];
#pragma unroll
        for (int ks = 0; ks < 3; ++ks)
            A[ks] = *(const short8*)&wt2[(16 * wu + m15) * 864 + kk * 96 + ks * 32 + quad * 8];

#pragma unroll
        for (int t = 0; t < 4; ++t) {
            const unsigned short* rp = scR + (16 * t + m15) * 128;
#pragma unroll
            for (int ks = 0; ks < 3; ++ks) {
                short8 Bv = *(const short8*)&rp[((ks * 4 + quad) ^ m15) << 3];
                acc[t] = MFMA(A[ks], Bv, acc[t]);
            }
        }

        // consume the prefetched loads and write the other buffer
        if (kk < 8) finishW(s_col + ((kk + 1) & 1) * 8192);
        if (kk < 8) __syncthreads();   // writes visible; reads of scR done
    }

    // ---------- Phase B epilogue ----------
    {
        float bs[4];
#pragma unroll
        for (int r2 = 0; r2 < 4; ++r2) bs[r2] = bias[16 * wu + quad * 4 + r2];
#pragma unroll
        for (int t = 0; t < 4; ++t) {
            int px = 16 * t + m15;
            size_t pbase = (size_t)ho * 128 + wo0 + px;
#pragma unroll
            for (int r2 = 0; r2 < 4; ++r2) {
                int o = 16 * wu + quad * 4 + r2;
                out[((size_t)b * 64 + o) * HW + pbase] = acc[t][r2] + bs[r2];
            }
        }
    }
}

// ------------------- fallback (no workspace): fp32 baseline -------------------
__global__ __launch_bounds__(256) void dcn_fb(
    const float* __restrict__ input,
    const float* __restrict__ wmain,
    const float* __restrict__ bias,
    const float* __restrict__ wom,
    const float* __restrict__ b_om,
    float* __restrict__ out)
{
    const int wo = blockIdx.x * 64 + threadIdx.x;
    const int ho = blockIdx.y * 4 + threadIdx.y;
    const int b  = blockIdx.z;
    const int p  = ho * 128 + wo;
    const float invH = 1.0f / 128.0f;
    const float* inb = input + (size_t)b * 64 * HW;

    float om[27];
#pragma unroll
    for (int oc = 0; oc < 27; ++oc) om[oc] = b_om[oc];

    for (int c = 0; c < 64; ++c) {
        const float* pc = inb + c * HW;
        float v[9];
#pragma unroll
        for (int kh = 0; kh < 3; ++kh) {
            int y = ho - 1 + kh;
            bool oky = (unsigned)y < 128u;
#pragma unroll
            for (int kw = 0; kw < 3; ++kw) {
                int x = wo - 1 + kw;
                bool ok = oky && ((unsigned)x < 128u);
                v[kh*3+kw] = ok ? pc[y * 128 + x] : 0.0f;
            }
        }
#pragma unroll
        for (int oc = 0; oc < 27; ++oc)
#pragma unroll
            for (int i = 0; i < 9; ++i)
                om[oc] = fmaf(v[i], wom[oc*594 + c*9 + i], om[oc]);
    }
    {
        float v64[9], v65[9];
#pragma unroll
        for (int kh = 0; kh < 3; ++kh) {
            int y = ho - 1 + kh;
            bool oky = (unsigned)y < 128u;
#pragma unroll
            for (int kw = 0; kw < 3; ++kw) {
                int x = wo - 1 + kw;
                bool ok = oky && ((unsigned)x < 128u);
                v64[kh*3+kw] = ok ? y * invH : 0.0f;
                v65[kh*3+kw] = ok ? (x * invH - 0.5f) : 0.0f;
            }
        }
#pragma unroll
        for (int oc = 0; oc < 27; ++oc)
#pragma unroll
            for (int i = 0; i < 9; ++i) {
                om[oc] = fmaf(v64[i], wom[oc*594 + 64*9 + i], om[oc]);
                om[oc] = fmaf(v65[i], wom[oc*594 + 65*9 + i], om[oc]);
            }
    }

    const float hg = ho * invH;
    const float wg = wo * invH - 0.5f;
    float* out_idx = out + (size_t)8 * 64 * HW;
    float* out_msk = out_idx + (size_t)8 * 18 * HW;
#pragma unroll
    for (int cc = 0; cc < 9; ++cc)
        out_idx[((size_t)b*18 + cc)*HW + p] = hg + (float)(cc/3 - 1) + om[cc];
#pragma unroll
    for (int cc = 9; cc < 18; ++cc)
        out_idx[((size_t)b*18 + cc)*HW + p] = wg + (float)((cc-9)%3 - 1) + om[cc];

    float mk[9];
#pragma unroll
    for (int kk = 0; kk < 9; ++kk) {
        mk[kk] = 1.0f / (1.0f + __expf(-om[18+kk]));
        out_msk[((size_t)b*9 + kk)*HW + p] = mk[kk];
    }

    float acc[64];
#pragma unroll
    for (int o = 0; o < 64; ++o) acc[o] = bias[o];

#pragma unroll
    for (int kk = 0; kk < 9; ++kk) {
        float ph = om[2*kk]   + (float)(kk/3) + (float)(ho - 1);
        float pw = om[2*kk+1] + (float)(kk%3) + (float)(wo - 1);
        float h0f = floorf(ph), w0f = floorf(pw);
        int h0 = (int)h0f, w0 = (int)w0f;
        int h1 = h0 + 1, w1 = w0 + 1;
        float lh = ph - h0f, lw = pw - w0f;
        float hh = 1.0f - lh, hwp = 1.0f - lw;
        float m = mk[kk];
        bool okh0 = (unsigned)h0 < 128u, okh1 = (unsigned)h1 < 128u;
        bool okw0 = (unsigned)w0 < 128u, okw1 = (unsigned)w1 < 128u;
        float w00 = (okh0 && okw0) ? hh*hwp*m : 0.0f;
        float w01 = (okh0 && okw1) ? hh*lw*m  : 0.0f;
        float w10 = (okh1 && okw0) ? lh*hwp*m : 0.0f;
        float w11 = (okh1 && okw1) ? lh*lw*m  : 0.0f;
        int h0c = min(max(h0, 0), 127), h1c = min(max(h1, 0), 127);
        int w0c = min(max(w0, 0), 127), w1c = min(max(w1, 0), 127);
        int o00 = h0c*128 + w0c, o01 = h0c*128 + w1c;
        int o10 = h1c*128 + w0c, o11 = h1c*128 + w1c;

        for (int c = 0; c < 64; ++c) {
            const float* pc = inb + c * HW;
            float col = w00*pc[o00] + w01*pc[o01] + w10*pc[o10] + w11*pc[o11];
#pragma unroll
            for (int o = 0; o < 64; ++o)
                acc[o] = fmaf(col, wmain[o*594 + c*9 + kk], acc[o]);
        }
        {
            float y0 = h0c * invH, y1 = h1c * invH;
            float x0 = w0c * invH - 0.5f, x1 = w1c * invH - 0.5f;
            float col64 = (w00 + w01)*y0 + (w10 + w11)*y1;
            float col65 = (w00 + w10)*x0 + (w01 + w11)*x1;
#pragma unroll
            for (int o = 0; o < 64; ++o) {
                acc[o] = fmaf(col64, wmain[o*594 + 64*9 + kk], acc[o]);
                acc[o] = fmaf(col65, wmain[o*594 + 65*9 + kk], acc[o]);
            }
        }
    }

#pragma unroll
    for (int o = 0; o < 64; ++o)
        out[((size_t)b*64 + o)*HW + p] = acc[o];
}

extern "C" void kernel_launch(void* const* d_in, const int* in_sizes, int n_in,
                              void* d_out, int out_size, void* d_ws, size_t ws_size,
                              hipStream_t stream)
{
    const float* input  = (const float*)d_in[0];
    const float* weight = (const float*)d_in[1];
    const float* bias   = (const float*)d_in[2];
    const float* w_om   = (const float*)d_in[3];
    const float* b_om   = (const float*)d_in[4];
    float* out = (float*)d_out;

    if (ws_size >= (size_t)WS_NEED) {
        unsigned short* wt2 = (unsigned short*)d_ws;
        float* wmt = (float*)((char*)d_ws + WT2_BYTES);
        int total = WT2_ELEMS + WMT_ELEMS;
        prep_w<<<(total + 255) / 256, 256, 0, stream>>>(weight, w_om, wt2, wmt);
        dim3 grid(2, 128, 8);
        dcn_hybrid5<<<grid, dim3(256, 1, 1), 0, stream>>>(input, wt2, bias, wmt, b_om, out);
    } else {
        dim3 grid(2, 32, 8);
        dcn_fb<<<grid, dim3(64, 4, 1), 0, stream>>>(input, weight, bias, w_om, b_om, out);
    }
}